// Round 1
// baseline (509.752 us; speedup 1.0000x reference)
//
#include <hip/hip_runtime.h>
#include <math.h>

// Problem dims (fixed by reference setup_inputs): (B=4, C=1, D=160, H=192, W=192) f32
#define BDIM 4
#define DDIM 160
#define HDIM 192
#define WDIM 192
#define NTOT (BDIM * DDIM * HDIM * WDIM)  // 23,592,960

// Output tile per block
#define TD 8
#define TH 8
#define TW 32
// Halo'd extents (7-tap blur -> +3 each side)
#define HD (TD + 6)   // 14
#define HH (TH + 6)   // 14
#define HW (TW + 6)   // 38

#define NTHREADS 512

// Normalized Gaussian, window=7, sigma=1.5 (computed in double, rounded to f32)
__device__ __constant__ float G7[7] = {
    0.03663285f, 0.11128076f, 0.21674532f, 0.27068215f,
    0.21674532f, 0.11128076f, 0.03663285f
};

__global__ __launch_bounds__(NTHREADS, 1)
void nq_main(const float* __restrict__ X,   // recon
             const float* __restrict__ Y,   // target
             float* __restrict__ acc)       // [0]=ssim_sum [1]=l1_num [2]=l1_den
{
    __shared__ float s1[5][TD][HH][HW];   // after D-blur: 5*8*14*38 = 85,120 B
    __shared__ float s2[5][TD][TH][HW];   // after H-blur: 5*8*8*38  = 48,640 B
    __shared__ float red[NTHREADS / 64][3];

    const int wt = blockIdx.x;            // 0..5
    const int ht = blockIdx.y;            // 0..23
    const int zt = blockIdx.z;            // 0..79 = b*20 + dt
    const int dt = zt % (DDIM / TD);
    const int b  = zt / (DDIM / TD);
    const int d0 = dt * TD, h0 = ht * TH, w0 = wt * TW;
    const long long base = (long long)b * DDIM * HDIM * WDIM;

    const int tid = threadIdx.x;

    float ssum = 0.f, l1n = 0.f, l1d = 0.f;

    // ---------------- stage 1: global load + D-blur (sliding in registers) ---------
    for (int col = tid; col < HH * HW; col += NTHREADS) {
        const int hh = col / HW;
        const int ww = col - hh * HW;
        const int h = h0 + hh - 3;
        const int w = w0 + ww - 3;
        const bool okhw = ((unsigned)h < HDIM) && ((unsigned)w < WDIM);

        float xv[HD], yv[HD];
        #pragma unroll
        for (int dd = 0; dd < HD; ++dd) {
            const int d = d0 + dd - 3;
            const bool ok = okhw && ((unsigned)d < DDIM);
            const long long idx = base + ((long long)d * HDIM + h) * WDIM + w;
            xv[dd] = ok ? X[idx] : 0.f;
            yv[dd] = ok ? Y[idx] : 0.f;
        }

        // fused weighted-L1: only interior elements (each global voxel is interior
        // of exactly one block since tiles partition the volume exactly)
        if (hh >= 3 && hh < 3 + TH && ww >= 3 && ww < 3 + TW) {
            #pragma unroll
            for (int dd = 3; dd < 3 + TD; ++dd) {
                const float xr = xv[dd], yr = yv[dd];
                const float wgt = (yr > -0.9f) ? 5.f : 1.f;
                l1n += wgt * fabsf(xr - yr);
                l1d += wgt;
            }
        }

        // 5 fields: x, y, x*x, y*y, x*y — blur along D, 8 outputs
        #pragma unroll
        for (int od = 0; od < TD; ++od) {
            float a0 = 0.f, a1 = 0.f, a2 = 0.f, a3 = 0.f, a4 = 0.f;
            #pragma unroll
            for (int k = 0; k < 7; ++k) {
                const float g = G7[k];
                const float xx = xv[od + k];
                const float yy = yv[od + k];
                const float gx = g * xx;
                const float gy = g * yy;
                a0 += gx;
                a1 += gy;
                a2 += gx * xx;
                a3 += gy * yy;
                a4 += gx * yy;
            }
            s1[0][od][hh][ww] = a0;
            s1[1][od][hh][ww] = a1;
            s1[2][od][hh][ww] = a2;
            s1[3][od][hh][ww] = a3;
            s1[4][od][hh][ww] = a4;
        }
    }
    __syncthreads();

    // ---------------- stage 2: H-blur -------------------------------------------
    for (int item = tid; item < 5 * TD * HW; item += NTHREADS) {  // 1520 items
        const int f   = item / (TD * HW);
        const int rem = item - f * (TD * HW);
        const int d   = rem / HW;
        const int w   = rem - d * HW;

        float v[HH];
        #pragma unroll
        for (int hh = 0; hh < HH; ++hh) v[hh] = s1[f][d][hh][w];

        #pragma unroll
        for (int oh = 0; oh < TH; ++oh) {
            float a = 0.f;
            #pragma unroll
            for (int k = 0; k < 7; ++k) a += G7[k] * v[oh + k];
            s2[f][d][oh][w] = a;
        }
    }
    __syncthreads();

    // ---------------- stage 3: W-blur + SSIM map + accumulate --------------------
    const float C1 = 4.0e-4f;   // (0.01*2)^2
    const float C2 = 3.6e-3f;   // (0.03*2)^2
    for (int v = tid; v < TD * TH * TW; v += NTHREADS) {  // 2048 voxels, 4 per thread
        const int o = v & (TW - 1);
        const int h = (v / TW) & (TH - 1);
        const int d = v / (TW * TH);

        float bx = 0.f, by = 0.f, bxx = 0.f, byy = 0.f, bxy = 0.f;
        #pragma unroll
        for (int k = 0; k < 7; ++k) {
            const float g = G7[k];
            bx  += g * s2[0][d][h][o + k];
            by  += g * s2[1][d][h][o + k];
            bxx += g * s2[2][d][h][o + k];
            byy += g * s2[3][d][h][o + k];
            bxy += g * s2[4][d][h][o + k];
        }
        const float mux2 = bx * bx;
        const float muy2 = by * by;
        const float muxy = bx * by;
        const float sx2 = bxx - mux2;
        const float sy2 = byy - muy2;
        const float sxy = bxy - muxy;
        const float num = (2.f * muxy + C1) * (2.f * sxy + C2);
        const float den = (mux2 + muy2 + C1) * (sx2 + sy2 + C2);
        ssum += num / den;
    }

    // ---------------- block reduce + atomics -------------------------------------
    #pragma unroll
    for (int off = 32; off > 0; off >>= 1) {
        ssum += __shfl_down(ssum, off, 64);
        l1n  += __shfl_down(l1n,  off, 64);
        l1d  += __shfl_down(l1d,  off, 64);
    }
    const int wave = tid >> 6, lane = tid & 63;
    if (lane == 0) { red[wave][0] = ssum; red[wave][1] = l1n; red[wave][2] = l1d; }
    __syncthreads();
    if (tid == 0) {
        float s = 0.f, n = 0.f, dn = 0.f;
        #pragma unroll
        for (int i = 0; i < NTHREADS / 64; ++i) {
            s += red[i][0]; n += red[i][1]; dn += red[i][2];
        }
        atomicAdd(&acc[0], s);
        atomicAdd(&acc[1], n);
        atomicAdd(&acc[2], dn);
    }
}

__global__ void nq_final(const float* __restrict__ acc,
                         const float* __restrict__ vq,
                         float* __restrict__ out)
{
    const float ssim_mean = acc[0] / (float)NTOT;
    out[0] = acc[1] / acc[2] + 0.5f * (1.0f - ssim_mean) + vq[0];
}

extern "C" void kernel_launch(void* const* d_in, const int* in_sizes, int n_in,
                              void* d_out, int out_size, void* d_ws, size_t ws_size,
                              hipStream_t stream)
{
    const float* X  = (const float*)d_in[0];  // recon
    const float* Y  = (const float*)d_in[1];  // target
    const float* vq = (const float*)d_in[2];  // scalar
    float* out = (float*)d_out;
    float* acc = (float*)d_ws;

    hipMemsetAsync(acc, 0, 3 * sizeof(float), stream);

    dim3 grid(WDIM / TW, HDIM / TH, (DDIM / TD) * BDIM);  // 6 x 24 x 80
    nq_main<<<grid, NTHREADS, 0, stream>>>(X, Y, acc);
    nq_final<<<1, 1, 0, stream>>>(acc, vq, out);
}

// Round 2
// 318.729 us; speedup vs baseline: 1.5993x; 1.5993x over previous
//
#include <hip/hip_runtime.h>
#include <math.h>

// Problem dims (fixed by reference setup_inputs): (B=4, C=1, D=160, H=192, W=192) f32
#define BDIM 4
#define DDIM 160
#define HDIM 192
#define WDIM 192
#define NTOT (BDIM * DDIM * HDIM * WDIM)  // 23,592,960

// In-plane output tile per block; D handled by sliding window over a segment.
#define TH 16
#define TW 64
#define SEG 20                 // output D-slices per block
#define NSEG (DDIM / SEG)      // 8
#define NS (SEG + 6)           // input slices per block (halo 3 each side)
#define NTH 1024

#define RHH (TH + 6)           // 22  raw halo rows
#define RWW (TW + 6)           // 70  raw halo cols
#define NRAW (RHH * RWW)       // 1540
#define HBW 72                 // padded row stride for hb (16B-aligned rows)

// Normalized Gaussian, window=7, sigma=1.5 (matches f32 reference to 7 digits)
__device__ __constant__ float G7[7] = {
    0.03663285f, 0.11128076f, 0.21674532f, 0.27068215f,
    0.21674532f, 0.11128076f, 0.03663285f
};

__global__ __launch_bounds__(NTH, 4)
void nq_main(const float* __restrict__ X,   // recon
             const float* __restrict__ Y,   // target
             float* __restrict__ acc)       // [0]=ssim_sum [1]=l1_num [2]=l1_den
{
    __shared__ __align__(16) float2 rawxy[RHH][RWW];      // 12,320 B
    __shared__ __align__(16) float  hb[5][TH][HBW];       // 23,040 B (H-blurred)
    __shared__ __align__(16) float  wb[5][TH][TW];        // 20,480 B (H+W blurred)
    __shared__ float red[NTH / 64][3];

    const int wt  = blockIdx.x;           // 0..2
    const int ht  = blockIdx.y;           // 0..11
    const int b   = blockIdx.z >> 3;      // 0..3
    const int seg = blockIdx.z & 7;       // 0..7
    const int h0 = ht * TH, w0 = wt * TW;
    const int dbase = seg * SEG;
    const long long bbase = (long long)b * (DDIM * HDIM * WDIM);

    const int tid = threadIdx.x;
    const int ph  = tid >> 6;             // 0..15 output row
    const int pw  = tid & 63;             // 0..63 output col

    // ---- per-thread invariants for the raw-load phase (≤2 points/thread) ----
    int  goff0 = 0, goff1 = 0;
    bool ok0 = false, ok1 = false, int0 = false, int1 = false;
    {
        const int i0 = tid;
        const int hh = i0 / RWW, ww = i0 - hh * RWW;
        const int h = h0 + hh - 3, w = w0 + ww - 3;
        ok0  = ((unsigned)h < HDIM) && ((unsigned)w < WDIM);
        int0 = (hh >= 3) && (hh < 3 + TH) && (ww >= 3) && (ww < 3 + TW);
        goff0 = h * WDIM + w;
    }
    const bool has1 = (tid + NTH) < NRAW;   // tid < 516
    if (has1) {
        const int i1 = tid + NTH;
        const int hh = i1 / RWW, ww = i1 - hh * RWW;
        const int h = h0 + hh - 3, w = w0 + ww - 3;
        ok1  = ((unsigned)h < HDIM) && ((unsigned)w < WDIM);
        int1 = (hh >= 3) && (hh < 3 + TH) && (ww >= 3) && (ww < 3 + TW);
        goff1 = h * WDIM + w;
    }

    float ssum = 0.f, l1n = 0.f, l1d = 0.f;

    // 5 sliding windows along D (one output pixel per thread)
    float wn0[7], wn1[7], wn2[7], wn3[7], wn4[7];

    // ---- prologue: load slice ds=0 into registers ----
    float x0, y0, x1 = 0.f, y1 = 0.f;
    {
        const int d_g = dbase - 3;
        const bool dok = ((unsigned)d_g < DDIM);
        const long long sb = bbase + (long long)d_g * (HDIM * WDIM);
        x0 = (dok && ok0) ? X[sb + goff0] : 0.f;
        y0 = (dok && ok0) ? Y[sb + goff0] : 0.f;
        if (has1) {
            x1 = (dok && ok1) ? X[sb + goff1] : 0.f;
            y1 = (dok && ok1) ? Y[sb + goff1] : 0.f;
        }
    }

    for (int ds = 0; ds < NS; ++ds) {
        // ---- P1: commit prefetched slice to LDS; fused weighted-L1 ----
        rawxy[0][tid] = make_float2(x0, y0);          // flat index tid < 1540
        if (has1) (&rawxy[0][0])[tid + NTH] = make_float2(x1, y1);

        if (ds >= 3 && ds < 3 + SEG) {                // uniform: this d is an output slice
            if (int0) {
                const float wgt = (y0 > -0.9f) ? 5.f : 1.f;
                l1n += wgt * fabsf(x0 - y0);
                l1d += wgt;
            }
            if (has1 && int1) {
                const float wgt = (y1 > -0.9f) ? 5.f : 1.f;
                l1n += wgt * fabsf(x1 - y1);
                l1d += wgt;
            }
        }
        __syncthreads();

        // ---- issue next slice's global loads (complete during P2/P3/P4) ----
        if (ds + 1 < NS) {
            const int d_g = dbase - 3 + ds + 1;
            const bool dok = ((unsigned)d_g < DDIM);
            const long long sb = bbase + (long long)d_g * (HDIM * WDIM);
            x0 = (dok && ok0) ? X[sb + goff0] : 0.f;
            y0 = (dok && ok0) ? Y[sb + goff0] : 0.f;
            if (has1) {
                x1 = (dok && ok1) ? X[sb + goff1] : 0.f;
                y1 = (dok && ok1) ? Y[sb + goff1] : 0.f;
            }
        }

        // ---- P2: H-blur + pointwise products: raw(22x70) -> hb[5](16x70) ----
        for (int i = tid; i < TH * RWW; i += NTH) {   // 1120 items
            const int ih = i / RWW, iw = i - ih * RWW;
            float a0 = 0.f, a1 = 0.f, a2 = 0.f, a3 = 0.f, a4 = 0.f;
            #pragma unroll
            for (int k = 0; k < 7; ++k) {
                const float2 p = rawxy[ih + k][iw];
                const float g = G7[k];
                const float gx = g * p.x, gy = g * p.y;
                a0 += gx;
                a1 += gy;
                a2 += gx * p.x;
                a3 += gy * p.y;
                a4 += gx * p.y;
            }
            hb[0][ih][iw] = a0;
            hb[1][ih][iw] = a1;
            hb[2][ih][iw] = a2;
            hb[3][ih][iw] = a3;
            hb[4][ih][iw] = a4;
        }
        __syncthreads();

        // ---- P3: W-blur, vectorized: hb[5](16x70) -> wb[5](16x64) ----
        for (int i = tid; i < 5 * TH * 16; i += NTH) { // 1280 items (4 outputs each)
            const int f  = i >> 8;
            const int r  = i & 255;
            const int ih = r >> 4;
            const int wq = (r & 15) << 2;              // 0,4,...,60
            const float* row = &hb[f][ih][0];
            const float4 q0 = *reinterpret_cast<const float4*>(row + wq);
            const float4 q1 = *reinterpret_cast<const float4*>(row + wq + 4);
            const float2 q2 = *reinterpret_cast<const float2*>(row + wq + 8);
            float v[10] = {q0.x, q0.y, q0.z, q0.w, q1.x, q1.y, q1.z, q1.w, q2.x, q2.y};
            float o[4];
            #pragma unroll
            for (int j = 0; j < 4; ++j) {
                float a = 0.f;
                #pragma unroll
                for (int k = 0; k < 7; ++k) a += G7[k] * v[j + k];
                o[j] = a;
            }
            *reinterpret_cast<float4*>(&wb[f][ih][wq]) = make_float4(o[0], o[1], o[2], o[3]);
        }
        __syncthreads();

        // ---- P4: push into D-window; emit SSIM once window is full ----
        {
            const float v0 = wb[0][ph][pw];
            const float v1 = wb[1][ph][pw];
            const float v2 = wb[2][ph][pw];
            const float v3 = wb[3][ph][pw];
            const float v4 = wb[4][ph][pw];
            #pragma unroll
            for (int j = 0; j < 6; ++j) {
                wn0[j] = wn0[j + 1]; wn1[j] = wn1[j + 1]; wn2[j] = wn2[j + 1];
                wn3[j] = wn3[j + 1]; wn4[j] = wn4[j + 1];
            }
            wn0[6] = v0; wn1[6] = v1; wn2[6] = v2; wn3[6] = v3; wn4[6] = v4;

            if (ds >= 6) {                             // uniform branch
                float bx = 0.f, by = 0.f, bxx = 0.f, byy = 0.f, bxy = 0.f;
                #pragma unroll
                for (int k = 0; k < 7; ++k) {
                    const float g = G7[k];
                    bx  += g * wn0[k];
                    by  += g * wn1[k];
                    bxx += g * wn2[k];
                    byy += g * wn3[k];
                    bxy += g * wn4[k];
                }
                const float C1 = 4.0e-4f;              // (0.01*2)^2
                const float C2 = 3.6e-3f;              // (0.03*2)^2
                const float mux2 = bx * bx;
                const float muy2 = by * by;
                const float muxy = bx * by;
                const float sx2 = bxx - mux2;
                const float sy2 = byy - muy2;
                const float sxy = bxy - muxy;
                const float num = (2.f * muxy + C1) * (2.f * sxy + C2);
                const float den = (mux2 + muy2 + C1) * (sx2 + sy2 + C2);
                ssum += num / den;
            }
        }
    }

    // ---- block reduce + atomics ----
    #pragma unroll
    for (int off = 32; off > 0; off >>= 1) {
        ssum += __shfl_down(ssum, off, 64);
        l1n  += __shfl_down(l1n,  off, 64);
        l1d  += __shfl_down(l1d,  off, 64);
    }
    const int wave = tid >> 6, lane = tid & 63;
    if (lane == 0) { red[wave][0] = ssum; red[wave][1] = l1n; red[wave][2] = l1d; }
    __syncthreads();
    if (tid == 0) {
        float s = 0.f, n = 0.f, dn = 0.f;
        #pragma unroll
        for (int i = 0; i < NTH / 64; ++i) {
            s += red[i][0]; n += red[i][1]; dn += red[i][2];
        }
        atomicAdd(&acc[0], s);
        atomicAdd(&acc[1], n);
        atomicAdd(&acc[2], dn);
    }
}

__global__ void nq_final(const float* __restrict__ acc,
                         const float* __restrict__ vq,
                         float* __restrict__ out)
{
    const float ssim_mean = acc[0] / (float)NTOT;
    out[0] = acc[1] / acc[2] + 0.5f * (1.0f - ssim_mean) + vq[0];
}

extern "C" void kernel_launch(void* const* d_in, const int* in_sizes, int n_in,
                              void* d_out, int out_size, void* d_ws, size_t ws_size,
                              hipStream_t stream)
{
    const float* X  = (const float*)d_in[0];  // recon
    const float* Y  = (const float*)d_in[1];  // target
    const float* vq = (const float*)d_in[2];  // scalar
    float* out = (float*)d_out;
    float* acc = (float*)d_ws;

    hipMemsetAsync(acc, 0, 3 * sizeof(float), stream);

    dim3 grid(WDIM / TW, HDIM / TH, BDIM * NSEG);     // 3 x 12 x 32 = 1152 blocks
    nq_main<<<grid, NTH, 0, stream>>>(X, Y, acc);
    nq_final<<<1, 1, 0, stream>>>(acc, vq, out);
}